// Round 14
// baseline (175.214 us; speedup 1.0000x reference)
//
#include <hip/hip_runtime.h>
#include <hip/hip_bf16.h>
#include <stdint.h>

// Problem: B=1, N=M=256, D=256, E=128, H=4, HD=32, P=64
typedef __hip_bfloat16 bf16;
typedef __attribute__((ext_vector_type(8))) short short8;
typedef __attribute__((ext_vector_type(4))) float f32x4;

__device__ __forceinline__ float b2f(bf16 v) { return __bfloat162float(v); }
__device__ __forceinline__ short f2bs(float f) {
    __hip_bfloat16 h = __float2bfloat16(f);
    return *reinterpret_cast<short*>(&h);
}
__device__ __forceinline__ float bs2f(short s) {
    union { uint32_t u; float f; } c; c.u = ((uint32_t)(uint16_t)s) << 16; return c.f;
}
// compile-time dtype loads (branch hoisted to kernel top)
template<bool F32> __device__ __forceinline__ float ldT(const void* p, int i) {
    if constexpr (F32) return ((const float*)p)[i];
    else               return b2f(((const bf16*)p)[i]);
}
template<bool F32> __device__ __forceinline__ short8 ldfragT(const void* p, int idx) {
    if constexpr (F32) {
        const float4* q = (const float4*)((const float*)p + idx);
        float4 a = q[0], b = q[1];
        short8 r;
        r[0]=f2bs(a.x); r[1]=f2bs(a.y); r[2]=f2bs(a.z); r[3]=f2bs(a.w);
        r[4]=f2bs(b.x); r[5]=f2bs(b.y); r[6]=f2bs(b.z); r[7]=f2bs(b.w);
        return r;
    } else {
        return *(const short8*)((const short*)p + idx);
    }
}
// per-block dtype detect: bf16 data -> low-half exponent field in [96,160]
__device__ __forceinline__ bool detect_f32(const void* x) {
    const uint32_t* w = (const uint32_t*)x;
    uint32_t v = w[threadIdx.x & 63];
    uint32_t e = (v >> 7) & 0xffu;
    unsigned long long m = __ballot(e >= 96 && e <= 160);
    return __popcll(m) < 40;
}

// workspace layout (float offsets)
#define OFF_QS    49416     // [256][128] q (scaled)                        (f32)
#define OFF_AX    82184     // [256][128] x @ phi_msg^T                     (f32)
#define OFF_AYP   114952    // [256][128] y @ phi_msg^T - phib              (f32)
#define OFF_GX    147720    // [256][128] x @ g_msg^T                       (f32)
#define OFF_GYP   180488    // [256][128] y @ g_msg^T - gb                  (f32)
#define OFF_PO    213256    // [128 c][4 h][256 q][32]  partial sum(exp*v)  (f32)
#define OFF_PL    4407560   // [128 c][4 h][256 q]      partial sum(exp)    (f32)
#define OFF_WPB   4538632   // [128][64]  bf16 phi_pe @ k_w2
#define OFF_WGB   4542728   // [128][64]  bf16 g_pe @ k_w2
#define OFF_HACT  4546824   // [256 m][256 key][64 p]  bf16 relu(u-w)  (4.19M shorts)
// total < 27 MB

// ---------------------------------------------------------------- role bodies (verbatim from round 13)
template<bool F32>
__device__ void ka5_body(int m, const void* xpos, const void* ypos,
                         const void* kw1, const void* kb1, float* ws,
                         float* skw1, float* skb1, float* swr)
{
    const int t = threadIdx.x;
    if (t < 192) skw1[t] = ldT<F32>(kw1, t);
    if (t < 64)  skb1[t] = ldT<F32>(kb1, t);
    __syncthreads();
    if (t < 64) {
        swr[t] = skw1[t*3+0]*ldT<F32>(ypos,m*3+0)
               + skw1[t*3+1]*ldT<F32>(ypos,m*3+1)
               + skw1[t*3+2]*ldT<F32>(ypos,m*3+2);
    }
    __syncthreads();
    float px = ldT<F32>(xpos,t*3+0), py = ldT<F32>(xpos,t*3+1), pz = ldT<F32>(xpos,t*3+2);
    short* dst = (short*)(ws + OFF_HACT) + ((size_t)m*256 + t)*64;
    #pragma unroll
    for (int i = 0; i < 8; ++i) {
        short8 v8;
        #pragma unroll
        for (int j = 0; j < 8; ++j) {
            int p = i*8 + j;
            float v = skw1[p*3+0]*px + skw1[p*3+1]*py + skw1[p*3+2]*pz
                    + skb1[p] - swr[p];
            v8[j] = f2bs(fmaxf(v, 0.f));
        }
        *(short8*)(dst + i*8) = v8;
    }
}

template<bool F32>
__device__ void ka2_body(int id, const void* phiw, const void* gw, const void* kw2, float* ws)
{
    const bool isP = (id < 8192);
    const void* src = isP ? phiw : gw;
    int i = isP ? id : id - 8192;
    int e = i >> 6, p = i & 63;
    float s = 0.f;
    #pragma unroll
    for (int k = 0; k < 16; ++k) {
        short8 a = ldfragT<F32>(src, e*384 + 256 + k*8);
        #pragma unroll
        for (int j = 0; j < 8; ++j)
            s += bs2f(a[j]) * ldT<F32>(kw2, (k*8+j)*64 + p);
    }
    ((short*)(ws + (isP ? OFF_WPB : OFF_WGB)))[i] = f2bs(s);
}

template<bool F32>
__device__ void ka3_body(int bi, const void* x, const void* y, const void* phiw,
                         const void* gw, const void* kb2, float* ws, float* sbias)
{
    const int t = threadIdx.x;
    const int w = t >> 6, lane = t & 63, quad = lane >> 4, l16 = lane & 15;
    const int which = bi >> 4, rg = bi & 15;
    const void* am = (which & 1) ? y : x;
    const void* wm = (which < 2) ? phiw : gw;
    if (t < 128) {
        float s = 0.f;
        if (which & 1) {
            const void* pw = (which == 1) ? phiw : gw;
            #pragma unroll
            for (int k = 0; k < 16; ++k) {
                short8 a  = ldfragT<F32>(pw,  t*384 + 256 + k*8);
                short8 bb = ldfragT<F32>(kb2, k*8);
                #pragma unroll
                for (int j = 0; j < 8; ++j) s += bs2f(a[j]) * bs2f(bb[j]);
            }
        }
        sbias[t] = s;
    }
    __syncthreads();
    const int row0 = rg*16;
    f32x4 acc[2];
    #pragma unroll
    for (int c2 = 0; c2 < 2; ++c2) { acc[c2][0]=0.f; acc[c2][1]=0.f; acc[c2][2]=0.f; acc[c2][3]=0.f; }
    #pragma unroll 2
    for (int k = 0; k < 8; ++k) {
        short8 af = ldfragT<F32>(am, (row0 + l16)*256 + k*32 + quad*8);
        #pragma unroll
        for (int c2 = 0; c2 < 2; ++c2) {
            int ct = w*2 + c2;
            short8 bf = ldfragT<F32>(wm, (ct*16 + l16)*384 + k*32 + quad*8);
            acc[c2] = __builtin_amdgcn_mfma_f32_16x16x32_bf16(af, bf, acc[c2], 0, 0, 0);
        }
    }
    const int base = (which==0) ? OFF_AX : (which==1) ? OFF_AYP : (which==2) ? OFF_GX : OFF_GYP;
    #pragma unroll
    for (int c2 = 0; c2 < 2; ++c2) {
        int col = (w*2+c2)*16 + l16;
        #pragma unroll
        for (int r = 0; r < 4; ++r)
            ws[base + (row0 + quad*4 + r)*128 + col] = acc[c2][r] - sbias[col];
    }
}

template<bool F32>
__device__ void ka4_body(int row0, const void* x, const void* xpos, const void* thw,
                         const void* qw1, const void* qb1,
                         const void* qw2, const void* qb2,
                         float* ws, char* smem)
{
    const int t = threadIdx.x;
    const int w = t >> 6, lane = t & 63, quad = lane >> 4, l16 = lane & 15;
    short* qpe_lds = (short*)smem;              // [16][128] bf16
    short* hq_lds  = (short*)(smem + 4096);     // [16][64]  bf16
    {
        int row = t >> 4, p0 = (t & 15)*4;
        float px = ldT<F32>(xpos,(row0+row)*3+0);
        float py = ldT<F32>(xpos,(row0+row)*3+1);
        float pz = ldT<F32>(xpos,(row0+row)*3+2);
        #pragma unroll
        for (int i = 0; i < 4; ++i) {
            int p = p0 + i;
            float v = ldT<F32>(qw1,p*3+0)*px + ldT<F32>(qw1,p*3+1)*py
                    + ldT<F32>(qw1,p*3+2)*pz + ldT<F32>(qb1,p);
            hq_lds[row*64 + p] = f2bs(fmaxf(v, 0.f));
        }
    }
    __syncthreads();
    {
        const short8 a0 = *(const short8*)(hq_lds + l16*64 + quad*8);
        const short8 a1 = *(const short8*)(hq_lds + l16*64 + 32 + quad*8);
        #pragma unroll
        for (int c2 = 0; c2 < 2; ++c2) {
            int ct = w*2 + c2;
            f32x4 acc; acc[0]=0.f; acc[1]=0.f; acc[2]=0.f; acc[3]=0.f;
            short8 b0 = ldfragT<F32>(qw2, (ct*16+l16)*64 + quad*8);
            short8 b1 = ldfragT<F32>(qw2, (ct*16+l16)*64 + 32 + quad*8);
            acc = __builtin_amdgcn_mfma_f32_16x16x32_bf16(a0, b0, acc, 0, 0, 0);
            acc = __builtin_amdgcn_mfma_f32_16x16x32_bf16(a1, b1, acc, 0, 0, 0);
            float qb = ldT<F32>(qb2, ct*16+l16);
            #pragma unroll
            for (int r = 0; r < 4; ++r)
                qpe_lds[(quad*4 + r)*128 + ct*16 + l16] = f2bs(acc[r] + qb);
        }
    }
    __syncthreads();
    f32x4 acc[2];
    #pragma unroll
    for (int c2 = 0; c2 < 2; ++c2) { acc[c2][0]=0.f; acc[c2][1]=0.f; acc[c2][2]=0.f; acc[c2][3]=0.f; }
    for (int k = 0; k < 12; ++k) {
        const short8 af = (k < 8)
            ? ldfragT<F32>(x, (row0 + l16)*256 + k*32 + quad*8)
            : *(const short8*)(qpe_lds + l16*128 + (k-8)*32 + quad*8);
        #pragma unroll
        for (int c2 = 0; c2 < 2; ++c2) {
            int ct = w*2 + c2;
            short8 bf = ldfragT<F32>(thw, (ct*16+l16)*384 + k*32 + quad*8);
            acc[c2] = __builtin_amdgcn_mfma_f32_16x16x32_bf16(af, bf, acc[c2], 0, 0, 0);
        }
    }
    #pragma unroll
    for (int c2 = 0; c2 < 2; ++c2)
        #pragma unroll
        for (int r = 0; r < 4; ++r)
            ws[OFF_QS + (row0 + quad*4 + r)*128 + (w*2+c2)*16 + l16] =
                acc[c2][r] * 0.17677669529663687f;   // * HD^-0.5
}

// ---------------------------------------------------------------- KA_ALL: all prep roles, one launch
// [0,256) hact | [256,320) wpb/wgb | [320,384) kproj | [384,400) q
template<bool F32>
__device__ void ka_all_body(
    const void* x, const void* y, const void* xpos, const void* ypos,
    const void* thw, const void* phiw, const void* gw,
    const void* qw1, const void* qb1, const void* qw2, const void* qb2,
    const void* kw1, const void* kb1, const void* kw2, const void* kb2,
    float* ws, char* smem)
{
    const int b = blockIdx.x;
    if (b < 256) {
        float* f = (float*)smem;
        ka5_body<F32>(b, xpos, ypos, kw1, kb1, ws, f, f + 192, f + 256);
    } else if (b < 320) {
        ka2_body<F32>((b - 256)*256 + threadIdx.x, phiw, gw, kw2, ws);
    } else if (b < 384) {
        ka3_body<F32>(b - 320, x, y, phiw, gw, kb2, ws, (float*)smem);
    } else {
        ka4_body<F32>((b - 384)*16, x, xpos, thw, qw1, qb1, qw2, qb2, ws, smem);
    }
}
__global__ void __launch_bounds__(256) ka_all(
    const void* __restrict__ x,    const void* __restrict__ y,
    const void* __restrict__ xpos, const void* __restrict__ ypos,
    const void* __restrict__ thw,  const void* __restrict__ phiw,
    const void* __restrict__ gw,
    const void* __restrict__ qw1,  const void* __restrict__ qb1,
    const void* __restrict__ qw2,  const void* __restrict__ qb2,
    const void* __restrict__ kw1,  const void* __restrict__ kb1,
    const void* __restrict__ kw2,  const void* __restrict__ kb2,
    float* __restrict__ ws)
{
    __shared__ alignas(16) char smem[6400];
    if (detect_f32(x))
        ka_all_body<true >(x,y,xpos,ypos,thw,phiw,gw,qw1,qb1,qw2,qb2,kw1,kb1,kw2,kb2,ws,smem);
    else
        ka_all_body<false>(x,y,xpos,ypos,thw,phiw,gw,qw1,qb1,qw2,qb2,kw1,kb1,kw2,kb2,ws,smem);
}

// ---------------------------------------------------------------- K3: MFMA k/v build + attention partials
// grid (c=128 chunks x 2 m, h=4), 512 threads (8 waves), 2 blocks/CU (72.5 KB LDS).
// Each wave covers 32 queries (2 q-tiles) -> every (m,h) K/V tile built exactly once,
// and each k/v LDS fragment read feeds 2 score + 2 PV MFMAs. hact staged into LDS
// from the precomputed global array; m+1 prefetched into regs during attn(m).
// K stored in permuted slots so exp(S^T) lands directly in PV A-operand registers.
__global__ void __launch_bounds__(512, 4) k3_attn(float* __restrict__ ws)
{
    const int c = blockIdx.x, h = blockIdx.y;
    const int tid = threadIdx.x;
    const int w = tid >> 6, lane = tid & 63;
    const int quad = lane >> 4, l16 = lane & 15;

    __shared__ alignas(16) short s_hact[256*72];   // 36 KB (staged)
    __shared__ alignas(16) short s_k[256*40];      // 20 KB (permuted slots)
    __shared__ alignas(16) short s_vt[32*264];     // 16.5 KB

    short8 qa[2];   // Q[q=l16][d=quad*8+j] per q-tile — B-operand of S^T = K·Q^T
    #pragma unroll
    for (int qt2 = 0; qt2 < 2; ++qt2) {
        const float* qp = ws + OFF_QS + (size_t)(w*32 + qt2*16 + l16)*128 + h*32 + quad*8;
        #pragma unroll
        for (int j = 0; j < 8; ++j) qa[qt2][j] = f2bs(qp[j]);
    }

    f32x4 o[2][2];
    float lpq[2] = {0.f, 0.f};
    #pragma unroll
    for (int a = 0; a < 2; ++a)
        #pragma unroll
        for (int d = 0; d < 2; ++d) { o[a][d][0]=0.f; o[a][d][1]=0.f; o[a][d][2]=0.f; o[a][d][3]=0.f; }

    const int which = w & 1, dtb = (w >> 1) & 1, ktg = w >> 2;
    const short* wbm = (const short*)(ws + (which ? OFF_WGB : OFF_WPB));
    const int ecol = h*32 + dtb*16 + l16;
    const short8 wb0 = *(const short8*)(wbm + ecol*64 + quad*8);
    const short8 wb1 = *(const short8*)(wbm + ecol*64 + 32 + quad*8);
    const float* xb  = ws + (which ? OFF_GX : OFF_AX);
    const float* ybp = ws + (which ? OFF_GYP : OFF_AYP);
    const short* hact = (const short*)(ws + OFF_HACT);

    const int skey = tid >> 1, shalf = tid & 1;
    uint4* const sdst = (uint4*)(s_hact + skey*72 + shalf*32);

    {   // stage m = c*2
        const uint4* src = (const uint4*)(hact + ((size_t)(c*2)*256 + skey)*64 + shalf*32);
        uint4 v0 = src[0], v1 = src[1], v2 = src[2], v3 = src[3];
        sdst[0] = v0; sdst[1] = v1; sdst[2] = v2; sdst[3] = v3;
    }
    __syncthreads();

    for (int mi = 0; mi < 2; ++mi) {
        const int m = c*2 + mi;
        const float ycol = ybp[m*128 + ecol];

        {   // K/V build via MFMA from staged s_hact
            #pragma unroll 2
            for (int i = 0; i < 8; ++i) {
                const int kt = ktg*8 + i;
                f32x4 acc;
                #pragma unroll
                for (int r = 0; r < 4; ++r)
                    acc[r] = xb[(size_t)(kt*16 + quad*4 + r)*128 + ecol] - ycol;
                const short8 a0 = *(const short8*)(s_hact + (kt*16 + l16)*72 + quad*8);
                const short8 a1 = *(const short8*)(s_hact + (kt*16 + l16)*72 + 32 + quad*8);
                acc = __builtin_amdgcn_mfma_f32_16x16x32_bf16(a0, wb0, acc, 0, 0, 0);
                acc = __builtin_amdgcn_mfma_f32_16x16x32_bf16(a1, wb1, acc, 0, 0, 0);
                if (which == 0) {
                    const int slot0 = (kt >> 1)*32 + (quad & 1)*16 + ((kt & 1)*2 + (quad >> 1))*4;
                    #pragma unroll
                    for (int r = 0; r < 4; ++r)
                        s_k[(slot0 + r)*40 + dtb*16 + l16] = f2bs(acc[r]);
                } else {
                    #pragma unroll
                    for (int r = 0; r < 4; ++r)
                        s_vt[(dtb*16 + l16)*264 + kt*16 + quad*4 + r] = f2bs(acc[r]);
                }
            }
        }
        __syncthreads();   // build done; s_hact now dead

        uint4 p0, p1, p2, p3;
        const bool pf = (mi < 1);
        if (pf) {
            const uint4* src = (const uint4*)(hact + ((size_t)(m+1)*256 + skey)*64 + shalf*32);
            p0 = src[0]; p1 = src[1]; p2 = src[2]; p3 = src[3];
        }

        for (int kc = 0; kc < 8; ++kc) {
            const short8 ka0 = *(const short8*)(s_k + (kc*32 + l16)*40 + quad*8);
            const short8 ka1 = *(const short8*)(s_k + (kc*32 + 16 + l16)*40 + quad*8);
            const short8 vb0 = *(const short8*)(s_vt + l16*264 + kc*32 + quad*8);
            const short8 vb1 = *(const short8*)(s_vt + (16 + l16)*264 + kc*32 + quad*8);
            #pragma unroll
            for (int qt2 = 0; qt2 < 2; ++qt2) {
                f32x4 z; z[0]=0.f; z[1]=0.f; z[2]=0.f; z[3]=0.f;
                f32x4 s0 = __builtin_amdgcn_mfma_f32_16x16x32_bf16(ka0, qa[qt2], z, 0, 0, 0);
                f32x4 s1 = __builtin_amdgcn_mfma_f32_16x16x32_bf16(ka1, qa[qt2], z, 0, 0, 0);
                short8 pfrag;
                #pragma unroll
                for (int r = 0; r < 4; ++r) {
                    float e0 = __expf(s0[r]);   // P[q=l16][k=quad*8+r]
                    float e1 = __expf(s1[r]);   // P[q=l16][k=quad*8+4+r]
                    lpq[qt2] += e0 + e1;
                    pfrag[r]   = f2bs(e0);
                    pfrag[r+4] = f2bs(e1);
                }
                o[qt2][0] = __builtin_amdgcn_mfma_f32_16x16x32_bf16(pfrag, vb0, o[qt2][0], 0, 0, 0);
                o[qt2][1] = __builtin_amdgcn_mfma_f32_16x16x32_bf16(pfrag, vb1, o[qt2][1], 0, 0, 0);
            }
        }

        if (pf) { sdst[0] = p0; sdst[1] = p1; sdst[2] = p2; sdst[3] = p3; }
        __syncthreads();
    }

    #pragma unroll
    for (int qt2 = 0; qt2 < 2; ++qt2) {
        const int q0 = w*32 + qt2*16;
        #pragma unroll
        for (int dtl = 0; dtl < 2; ++dtl)
            #pragma unroll
            for (int r = 0; r < 4; ++r)
                ws[OFF_PO + (size_t)((c*4 + h)*256 + q0 + quad*4 + r)*32 + dtl*16 + l16] = o[qt2][dtl][r];
        float v = lpq[qt2];
        v += __shfl_xor(v, 16);
        v += __shfl_xor(v, 32);
        if (lane < 16)
            ws[OFF_PL + (c*4 + h)*256 + q0 + lane] = v;
    }
}

// ---------------------------------------------------------------- K4 body (templated on dtype)
template<bool F32>
__device__ void k4_body(
    const float* __restrict__ ws, const void* __restrict__ x,
    const void* __restrict__ outw, const void* __restrict__ lng,
    const void* __restrict__ lnb, void* __restrict__ outp,
    float (*pl4)[256], float* red, float* o2, float* stat)
{
    int q = blockIdx.x, t = threadIdx.x;

    #pragma unroll
    for (int h = 0; h < 4; ++h)
        pl4[h][t] = (t < 128) ? ws[OFF_PL + (t*4 + h)*256 + q] : 0.f;
    __syncthreads();
    for (int s = 128; s > 0; s >>= 1) {
        if (t < s) {
            pl4[0][t] += pl4[0][t+s]; pl4[1][t] += pl4[1][t+s];
            pl4[2][t] += pl4[2][t+s]; pl4[3][t] += pl4[3][t+s];
        }
        __syncthreads();
    }
    int e = t & 127, h2 = e >> 5, d = e & 31, half = t >> 7;
    float a = 0.f;
    #pragma unroll
    for (int mm = 0; mm < 64; ++mm) {
        int c = half*64 + mm;
        a += ws[OFF_PO + ((c*4 + h2)*256 + q)*32 + d];
    }
    red[t] = a;
    __syncthreads();
    if (t < 128) o2[t] = (red[t] + red[t+128]) / pl4[t>>5][0];
    __syncthreads();

    float rv = ldT<F32>(x, q*256 + t);
    #pragma unroll
    for (int i = 0; i < 16; ++i) {
        short8 wv = ldfragT<F32>(outw, t*128 + i*8);
        #pragma unroll
        for (int j = 0; j < 8; ++j) rv += o2[i*8+j]*bs2f(wv[j]);
    }
    red[t] = rv; __syncthreads();
    for (int s = 128; s > 0; s >>= 1) { if (t < s) red[t] += red[t+s]; __syncthreads(); }
    if (t == 0) stat[0] = red[0] * (1.f/256.f);
    __syncthreads();
    float mu = stat[0];
    float dv = rv - mu;
    red[t] = dv*dv; __syncthreads();
    for (int s = 128; s > 0; s >>= 1) { if (t < s) red[t] += red[t+s]; __syncthreads(); }
    if (t == 0) stat[1] = red[0] * (1.f/256.f);
    __syncthreads();
    float rstd = rsqrtf(stat[1] + 1e-5f);
    float val = dv*rstd*ldT<F32>(lng,t) + ldT<F32>(lnb,t);
    if constexpr (F32) ((float*)outp)[q*256 + t] = val;
    else               ((bf16*)outp)[q*256 + t] = __float2bfloat16(val);
}

__global__ void __launch_bounds__(256) k4_out(
    const float* __restrict__ ws, const void* __restrict__ x,
    const void* __restrict__ outw, const void* __restrict__ lng,
    const void* __restrict__ lnb, void* __restrict__ outp)
{
    __shared__ float pl4[4][256];
    __shared__ float red[256];
    __shared__ float o2[128];
    __shared__ float stat[2];
    const bool f32 = detect_f32(x);
    if (f32) k4_body<true >(ws, x, outw, lng, lnb, outp, pl4, red, o2, stat);
    else     k4_body<false>(ws, x, outw, lng, lnb, outp, pl4, red, o2, stat);
}

// ----------------------------------------------------------------
extern "C" void kernel_launch(void* const* d_in, const int* in_sizes, int n_in,
                              void* d_out, int out_size, void* d_ws, size_t ws_size,
                              hipStream_t stream)
{
    const void* x    = d_in[0];
    const void* y    = d_in[1];
    const void* xpos = d_in[2];
    const void* ypos = d_in[3];
    const void* thw  = d_in[4];
    const void* phiw = d_in[5];
    const void* gw   = d_in[6];
    const void* qw1  = d_in[7];
    const void* qb1  = d_in[8];
    const void* qw2  = d_in[9];
    const void* qb2  = d_in[10];
    const void* kw1  = d_in[11];
    const void* kb1  = d_in[12];
    const void* kw2  = d_in[13];
    const void* kb2  = d_in[14];
    const void* outw = d_in[15];
    const void* lng  = d_in[16];
    const void* lnb  = d_in[17];
    float* ws = (float*)d_ws;

    ka_all<<<400, 256, 0, stream>>>(x, y, xpos, ypos, thw, phiw, gw,
                                    qw1, qb1, qw2, qb2, kw1, kb1, kw2, kb2, ws);
    k3_attn<<<dim3(128, 4), 512, 0, stream>>>(ws);
    k4_out<<<256, 256, 0, stream>>>(ws, x, outw, lng, lnb, d_out);
}

// Round 15
// 140.954 us; speedup vs baseline: 1.2431x; 1.2431x over previous
//
#include <hip/hip_runtime.h>
#include <hip/hip_bf16.h>
#include <stdint.h>

// Problem: B=1, N=M=256, D=256, E=128, H=4, HD=32, P=64
typedef __hip_bfloat16 bf16;
typedef __attribute__((ext_vector_type(8))) short short8;
typedef __attribute__((ext_vector_type(4))) float f32x4;

__device__ __forceinline__ float b2f(bf16 v) { return __bfloat162float(v); }
__device__ __forceinline__ short f2bs(float f) {
    __hip_bfloat16 h = __float2bfloat16(f);
    return *reinterpret_cast<short*>(&h);
}
__device__ __forceinline__ float bs2f(short s) {
    union { uint32_t u; float f; } c; c.u = ((uint32_t)(uint16_t)s) << 16; return c.f;
}
// compile-time dtype loads (branch hoisted to kernel top)
template<bool F32> __device__ __forceinline__ float ldT(const void* p, int i) {
    if constexpr (F32) return ((const float*)p)[i];
    else               return b2f(((const bf16*)p)[i]);
}
template<bool F32> __device__ __forceinline__ short8 ldfragT(const void* p, int idx) {
    if constexpr (F32) {
        const float4* q = (const float4*)((const float*)p + idx);
        float4 a = q[0], b = q[1];
        short8 r;
        r[0]=f2bs(a.x); r[1]=f2bs(a.y); r[2]=f2bs(a.z); r[3]=f2bs(a.w);
        r[4]=f2bs(b.x); r[5]=f2bs(b.y); r[6]=f2bs(b.z); r[7]=f2bs(b.w);
        return r;
    } else {
        return *(const short8*)((const short*)p + idx);
    }
}
// per-block dtype detect: bf16 data -> low-half exponent field in [96,160]
__device__ __forceinline__ bool detect_f32(const void* x) {
    const uint32_t* w = (const uint32_t*)x;
    uint32_t v = w[threadIdx.x & 63];
    uint32_t e = (v >> 7) & 0xffu;
    unsigned long long m = __ballot(e >= 96 && e <= 160);
    return __popcll(m) < 40;
}

// workspace layout (float offsets)
#define OFF_QS    49416     // [256][128] q (scaled)                        (f32)
#define OFF_AX    82184     // [256][128] x @ phi_msg^T                     (f32)
#define OFF_AYP   114952    // [256][128] y @ phi_msg^T - phib              (f32)
#define OFF_GX    147720    // [256][128] x @ g_msg^T                       (f32)
#define OFF_GYP   180488    // [256][128] y @ g_msg^T - gb                  (f32)
#define OFF_PO    213256    // [64 c][4 h][256 q][16] u32: packed bf16 pair (lo=col d, hi=col d+16)
#define OFF_PL    2310408   // [64 c][4 h][256 q]      partial sum(exp)     (f32)
#define OFF_WPB   2375944   // [128][64]  bf16 phi_pe @ k_w2
#define OFF_WGB   2380040   // [128][64]  bf16 g_pe @ k_w2
#define OFF_HACT  2384136   // [256 m][256 key][64 p]  bf16 relu(u-w)  (4.19M shorts)
// total < 18 MB

// ---------------------------------------------------------------- role bodies (verbatim from round 13)
template<bool F32>
__device__ void ka5_body(int m, const void* xpos, const void* ypos,
                         const void* kw1, const void* kb1, float* ws,
                         float* skw1, float* skb1, float* swr)
{
    const int t = threadIdx.x;
    if (t < 192) skw1[t] = ldT<F32>(kw1, t);
    if (t < 64)  skb1[t] = ldT<F32>(kb1, t);
    __syncthreads();
    if (t < 64) {
        swr[t] = skw1[t*3+0]*ldT<F32>(ypos,m*3+0)
               + skw1[t*3+1]*ldT<F32>(ypos,m*3+1)
               + skw1[t*3+2]*ldT<F32>(ypos,m*3+2);
    }
    __syncthreads();
    float px = ldT<F32>(xpos,t*3+0), py = ldT<F32>(xpos,t*3+1), pz = ldT<F32>(xpos,t*3+2);
    short* dst = (short*)(ws + OFF_HACT) + ((size_t)m*256 + t)*64;
    #pragma unroll
    for (int i = 0; i < 8; ++i) {
        short8 v8;
        #pragma unroll
        for (int j = 0; j < 8; ++j) {
            int p = i*8 + j;
            float v = skw1[p*3+0]*px + skw1[p*3+1]*py + skw1[p*3+2]*pz
                    + skb1[p] - swr[p];
            v8[j] = f2bs(fmaxf(v, 0.f));
        }
        *(short8*)(dst + i*8) = v8;
    }
}

template<bool F32>
__device__ void ka2_body(int id, const void* phiw, const void* gw, const void* kw2, float* ws)
{
    const bool isP = (id < 8192);
    const void* src = isP ? phiw : gw;
    int i = isP ? id : id - 8192;
    int e = i >> 6, p = i & 63;
    float s = 0.f;
    #pragma unroll
    for (int k = 0; k < 16; ++k) {
        short8 a = ldfragT<F32>(src, e*384 + 256 + k*8);
        #pragma unroll
        for (int j = 0; j < 8; ++j)
            s += bs2f(a[j]) * ldT<F32>(kw2, (k*8+j)*64 + p);
    }
    ((short*)(ws + (isP ? OFF_WPB : OFF_WGB)))[i] = f2bs(s);
}

template<bool F32>
__device__ void ka3_body(int bi, const void* x, const void* y, const void* phiw,
                         const void* gw, const void* kb2, float* ws, float* sbias)
{
    const int t = threadIdx.x;
    const int w = t >> 6, lane = t & 63, quad = lane >> 4, l16 = lane & 15;
    const int which = bi >> 4, rg = bi & 15;
    const void* am = (which & 1) ? y : x;
    const void* wm = (which < 2) ? phiw : gw;
    if (t < 128) {
        float s = 0.f;
        if (which & 1) {
            const void* pw = (which == 1) ? phiw : gw;
            #pragma unroll
            for (int k = 0; k < 16; ++k) {
                short8 a  = ldfragT<F32>(pw,  t*384 + 256 + k*8);
                short8 bb = ldfragT<F32>(kb2, k*8);
                #pragma unroll
                for (int j = 0; j < 8; ++j) s += bs2f(a[j]) * bs2f(bb[j]);
            }
        }
        sbias[t] = s;
    }
    __syncthreads();
    const int row0 = rg*16;
    f32x4 acc[2];
    #pragma unroll
    for (int c2 = 0; c2 < 2; ++c2) { acc[c2][0]=0.f; acc[c2][1]=0.f; acc[c2][2]=0.f; acc[c2][3]=0.f; }
    #pragma unroll 2
    for (int k = 0; k < 8; ++k) {
        short8 af = ldfragT<F32>(am, (row0 + l16)*256 + k*32 + quad*8);
        #pragma unroll
        for (int c2 = 0; c2 < 2; ++c2) {
            int ct = w*2 + c2;
            short8 bf = ldfragT<F32>(wm, (ct*16 + l16)*384 + k*32 + quad*8);
            acc[c2] = __builtin_amdgcn_mfma_f32_16x16x32_bf16(af, bf, acc[c2], 0, 0, 0);
        }
    }
    const int base = (which==0) ? OFF_AX : (which==1) ? OFF_AYP : (which==2) ? OFF_GX : OFF_GYP;
    #pragma unroll
    for (int c2 = 0; c2 < 2; ++c2) {
        int col = (w*2+c2)*16 + l16;
        #pragma unroll
        for (int r = 0; r < 4; ++r)
            ws[base + (row0 + quad*4 + r)*128 + col] = acc[c2][r] - sbias[col];
    }
}

template<bool F32>
__device__ void ka4_body(int row0, const void* x, const void* xpos, const void* thw,
                         const void* qw1, const void* qb1,
                         const void* qw2, const void* qb2,
                         float* ws, char* smem)
{
    const int t = threadIdx.x;
    const int w = t >> 6, lane = t & 63, quad = lane >> 4, l16 = lane & 15;
    short* qpe_lds = (short*)smem;              // [16][128] bf16
    short* hq_lds  = (short*)(smem + 4096);     // [16][64]  bf16
    {
        int row = t >> 4, p0 = (t & 15)*4;
        float px = ldT<F32>(xpos,(row0+row)*3+0);
        float py = ldT<F32>(xpos,(row0+row)*3+1);
        float pz = ldT<F32>(xpos,(row0+row)*3+2);
        #pragma unroll
        for (int i = 0; i < 4; ++i) {
            int p = p0 + i;
            float v = ldT<F32>(qw1,p*3+0)*px + ldT<F32>(qw1,p*3+1)*py
                    + ldT<F32>(qw1,p*3+2)*pz + ldT<F32>(qb1,p);
            hq_lds[row*64 + p] = f2bs(fmaxf(v, 0.f));
        }
    }
    __syncthreads();
    {
        const short8 a0 = *(const short8*)(hq_lds + l16*64 + quad*8);
        const short8 a1 = *(const short8*)(hq_lds + l16*64 + 32 + quad*8);
        #pragma unroll
        for (int c2 = 0; c2 < 2; ++c2) {
            int ct = w*2 + c2;
            f32x4 acc; acc[0]=0.f; acc[1]=0.f; acc[2]=0.f; acc[3]=0.f;
            short8 b0 = ldfragT<F32>(qw2, (ct*16+l16)*64 + quad*8);
            short8 b1 = ldfragT<F32>(qw2, (ct*16+l16)*64 + 32 + quad*8);
            acc = __builtin_amdgcn_mfma_f32_16x16x32_bf16(a0, b0, acc, 0, 0, 0);
            acc = __builtin_amdgcn_mfma_f32_16x16x32_bf16(a1, b1, acc, 0, 0, 0);
            float qb = ldT<F32>(qb2, ct*16+l16);
            #pragma unroll
            for (int r = 0; r < 4; ++r)
                qpe_lds[(quad*4 + r)*128 + ct*16 + l16] = f2bs(acc[r] + qb);
        }
    }
    __syncthreads();
    f32x4 acc[2];
    #pragma unroll
    for (int c2 = 0; c2 < 2; ++c2) { acc[c2][0]=0.f; acc[c2][1]=0.f; acc[c2][2]=0.f; acc[c2][3]=0.f; }
    for (int k = 0; k < 12; ++k) {
        const short8 af = (k < 8)
            ? ldfragT<F32>(x, (row0 + l16)*256 + k*32 + quad*8)
            : *(const short8*)(qpe_lds + l16*128 + (k-8)*32 + quad*8);
        #pragma unroll
        for (int c2 = 0; c2 < 2; ++c2) {
            int ct = w*2 + c2;
            short8 bf = ldfragT<F32>(thw, (ct*16+l16)*384 + k*32 + quad*8);
            acc[c2] = __builtin_amdgcn_mfma_f32_16x16x32_bf16(af, bf, acc[c2], 0, 0, 0);
        }
    }
    #pragma unroll
    for (int c2 = 0; c2 < 2; ++c2)
        #pragma unroll
        for (int r = 0; r < 4; ++r)
            ws[OFF_QS + (row0 + quad*4 + r)*128 + (w*2+c2)*16 + l16] =
                acc[c2][r] * 0.17677669529663687f;   // * HD^-0.5
}

// ---------------------------------------------------------------- KA_ALL: all prep roles, one launch
// [0,256) hact | [256,320) wpb/wgb | [320,384) kproj | [384,400) q
template<bool F32>
__device__ void ka_all_body(
    const void* x, const void* y, const void* xpos, const void* ypos,
    const void* thw, const void* phiw, const void* gw,
    const void* qw1, const void* qb1, const void* qw2, const void* qb2,
    const void* kw1, const void* kb1, const void* kw2, const void* kb2,
    float* ws, char* smem)
{
    const int b = blockIdx.x;
    if (b < 256) {
        float* f = (float*)smem;
        ka5_body<F32>(b, xpos, ypos, kw1, kb1, ws, f, f + 192, f + 256);
    } else if (b < 320) {
        ka2_body<F32>((b - 256)*256 + threadIdx.x, phiw, gw, kw2, ws);
    } else if (b < 384) {
        ka3_body<F32>(b - 320, x, y, phiw, gw, kb2, ws, (float*)smem);
    } else {
        ka4_body<F32>((b - 384)*16, x, xpos, thw, qw1, qb1, qw2, qb2, ws, smem);
    }
}
__global__ void __launch_bounds__(256) ka_all(
    const void* __restrict__ x,    const void* __restrict__ y,
    const void* __restrict__ xpos, const void* __restrict__ ypos,
    const void* __restrict__ thw,  const void* __restrict__ phiw,
    const void* __restrict__ gw,
    const void* __restrict__ qw1,  const void* __restrict__ qb1,
    const void* __restrict__ qw2,  const void* __restrict__ qb2,
    const void* __restrict__ kw1,  const void* __restrict__ kb1,
    const void* __restrict__ kw2,  const void* __restrict__ kb2,
    float* __restrict__ ws)
{
    __shared__ alignas(16) char smem[6400];
    if (detect_f32(x))
        ka_all_body<true >(x,y,xpos,ypos,thw,phiw,gw,qw1,qb1,qw2,qb2,kw1,kb1,kw2,kb2,ws,smem);
    else
        ka_all_body<false>(x,y,xpos,ypos,thw,phiw,gw,qw1,qb1,qw2,qb2,kw1,kb1,kw2,kb2,ws,smem);
}

// ---------------------------------------------------------------- K3: MFMA k/v build + attention partials
// grid (c=64, h=4, qh=2), 512 threads (8 waves), 2 blocks/CU (72.5 KB LDS).
// hact staged into LDS from the precomputed global array; m+1 slice prefetched into
// registers during attn(mi). K stored in permuted slots so exp(S^T) lands directly
// in PV A-operand registers (no P LDS round-trip). PO partials stored as packed
// bf16 pairs (lo=col d, hi=col d+16) -> half the epilogue traffic.
__global__ void __launch_bounds__(512, 4) k3_attn(float* __restrict__ ws)
{
    const int c = blockIdx.x, h = blockIdx.y, qh = blockIdx.z;
    const int tid = threadIdx.x;
    const int w = tid >> 6, lane = tid & 63;
    const int quad = lane >> 4, l16 = lane & 15;

    __shared__ alignas(16) short s_hact[256*72];   // 36 KB (staged)
    __shared__ alignas(16) short s_k[256*40];      // 20 KB (permuted slots)
    __shared__ alignas(16) short s_vt[32*264];     // 16.5 KB

    const int q0 = qh*128 + w*16;
    short8 qa;   // Q[q=l16][d=quad*8+j] — B-operand of S^T = K·Q^T
    {
        const float* qp = ws + OFF_QS + (size_t)(q0 + l16)*128 + h*32 + quad*8;
        #pragma unroll
        for (int j = 0; j < 8; ++j) qa[j] = f2bs(qp[j]);
    }

    f32x4 o[2];
    float lpq = 0.f;
    #pragma unroll
    for (int d = 0; d < 2; ++d) { o[d][0]=0.f; o[d][1]=0.f; o[d][2]=0.f; o[d][3]=0.f; }

    const int which = w & 1, dtb = (w >> 1) & 1, ktg = w >> 2;
    const short* wbm = (const short*)(ws + (which ? OFF_WGB : OFF_WPB));
    const int ecol = h*32 + dtb*16 + l16;
    const short8 wb0 = *(const short8*)(wbm + ecol*64 + quad*8);
    const short8 wb1 = *(const short8*)(wbm + ecol*64 + 32 + quad*8);
    const float* xb  = ws + (which ? OFF_GX : OFF_AX);
    const float* ybp = ws + (which ? OFF_GYP : OFF_AYP);
    const short* hact = (const short*)(ws + OFF_HACT);

    const int skey = tid >> 1, shalf = tid & 1;
    uint4* const sdst = (uint4*)(s_hact + skey*72 + shalf*32);

    {   // stage m = c*4
        const uint4* src = (const uint4*)(hact + ((size_t)(c*4)*256 + skey)*64 + shalf*32);
        uint4 v0 = src[0], v1 = src[1], v2 = src[2], v3 = src[3];
        sdst[0] = v0; sdst[1] = v1; sdst[2] = v2; sdst[3] = v3;
    }
    __syncthreads();

    for (int mi = 0; mi < 4; ++mi) {
        const int m = c*4 + mi;
        const float ycol = ybp[m*128 + ecol];

        {   // K/V build via MFMA from staged s_hact
            #pragma unroll 2
            for (int i = 0; i < 8; ++i) {
                const int kt = ktg*8 + i;
                f32x4 acc;
                #pragma unroll
                for (int r = 0; r < 4; ++r)
                    acc[r] = xb[(size_t)(kt*16 + quad*4 + r)*128 + ecol] - ycol;
                const short8 a0 = *(const short8*)(s_hact + (kt*16 + l16)*72 + quad*8);
                const short8 a1 = *(const short8*)(s_hact + (kt*16 + l16)*72 + 32 + quad*8);
                acc = __builtin_amdgcn_mfma_f32_16x16x32_bf16(a0, wb0, acc, 0, 0, 0);
                acc = __builtin_amdgcn_mfma_f32_16x16x32_bf16(a1, wb1, acc, 0, 0, 0);
                if (which == 0) {
                    const int slot0 = (kt >> 1)*32 + (quad & 1)*16 + ((kt & 1)*2 + (quad >> 1))*4;
                    #pragma unroll
                    for (int r = 0; r < 4; ++r)
                        s_k[(slot0 + r)*40 + dtb*16 + l16] = f2bs(acc[r]);
                } else {
                    #pragma unroll
                    for (int r = 0; r < 4; ++r)
                        s_vt[(dtb*16 + l16)*264 + kt*16 + quad*4 + r] = f2bs(acc[r]);
                }
            }
        }
        __syncthreads();   // build done; s_hact now dead

        uint4 p0, p1, p2, p3;
        const bool pf = (mi < 3);
        if (pf) {
            const uint4* src = (const uint4*)(hact + ((size_t)(m+1)*256 + skey)*64 + shalf*32);
            p0 = src[0]; p1 = src[1]; p2 = src[2]; p3 = src[3];
        }

        for (int kc = 0; kc < 8; ++kc) {
            const short8 ka0 = *(const short8*)(s_k + (kc*32 + l16)*40 + quad*8);
            const short8 ka1 = *(const short8*)(s_k + (kc*32 + 16 + l16)*40 + quad*8);
            const short8 vb0 = *(const short8*)(s_vt + l16*264 + kc*32 + quad*8);
            const short8 vb1 = *(const short8*)(s_vt + (16 + l16)*264 + kc*32 + quad*8);
            f32x4 z; z[0]=0.f; z[1]=0.f; z[2]=0.f; z[3]=0.f;
            f32x4 s0 = __builtin_amdgcn_mfma_f32_16x16x32_bf16(ka0, qa, z, 0, 0, 0);
            f32x4 s1 = __builtin_amdgcn_mfma_f32_16x16x32_bf16(ka1, qa, z, 0, 0, 0);
            short8 pfrag;
            #pragma unroll
            for (int r = 0; r < 4; ++r) {
                float e0 = __expf(s0[r]);   // P[q=l16][k=quad*8+r]
                float e1 = __expf(s1[r]);   // P[q=l16][k=quad*8+4+r]
                lpq += e0 + e1;
                pfrag[r]   = f2bs(e0);
                pfrag[r+4] = f2bs(e1);
            }
            o[0] = __builtin_amdgcn_mfma_f32_16x16x32_bf16(pfrag, vb0, o[0], 0, 0, 0);
            o[1] = __builtin_amdgcn_mfma_f32_16x16x32_bf16(pfrag, vb1, o[1], 0, 0, 0);
        }

        if (pf) { sdst[0] = p0; sdst[1] = p1; sdst[2] = p2; sdst[3] = p3; }
        __syncthreads();
    }

    {   // packed bf16 PO write: u32 = (col l16 | col 16+l16 << 16) per row
        uint32_t* po = (uint32_t*)(ws + OFF_PO);
        #pragma unroll
        for (int r = 0; r < 4; ++r) {
            uint32_t pk = (uint32_t)(uint16_t)f2bs(o[0][r])
                        | ((uint32_t)(uint16_t)f2bs(o[1][r]) << 16);
            po[(size_t)((c*4 + h)*256 + q0 + quad*4 + r)*16 + l16] = pk;
        }
    }
    {
        float v = lpq;
        v += __shfl_xor(v, 16);
        v += __shfl_xor(v, 32);
        if (lane < 16)
            ws[OFF_PL + (c*4 + h)*256 + q0 + lane] = v;
    }
}

// ---------------------------------------------------------------- K4 body (templated on dtype)
template<bool F32>
__device__ void k4_body(
    const float* __restrict__ ws, const void* __restrict__ x,
    const void* __restrict__ outw, const void* __restrict__ lng,
    const void* __restrict__ lnb, void* __restrict__ outp,
    float (*pl4)[256], float* red, float* o2, float* stat)
{
    int q = blockIdx.x, t = threadIdx.x;

    #pragma unroll
    for (int h = 0; h < 4; ++h)
        pl4[h][t] = (t < 64) ? ws[OFF_PL + (t*4 + h)*256 + q] : 0.f;
    __syncthreads();
    for (int s = 128; s > 0; s >>= 1) {
        if (t < s) {
            pl4[0][t] += pl4[0][t+s]; pl4[1][t] += pl4[1][t+s];
            pl4[2][t] += pl4[2][t+s]; pl4[3][t] += pl4[3][t+s];
        }
        __syncthreads();
    }
    int e = t & 127, h2 = e >> 5, d = e & 31, half = t >> 7;
    const uint32_t* po = (const uint32_t*)(ws + OFF_PO);
    const int pair = d & 15, hi = d >> 4;
    float a = 0.f;
    #pragma unroll
    for (int mm = 0; mm < 32; ++mm) {
        int c = half*32 + mm;
        uint32_t v = po[((c*4 + h2)*256 + q)*16 + pair];
        a += bs2f((short)(hi ? (v >> 16) : (v & 0xffffu)));
    }
    red[t] = a;
    __syncthreads();
    if (t < 128) o2[t] = (red[t] + red[t+128]) / pl4[t>>5][0];
    __syncthreads();

    float rv = ldT<F32>(x, q*256 + t);
    #pragma unroll
    for (int i = 0; i < 16; ++i) {
        short8 wv = ldfragT<F32>(outw, t*128 + i*8);
        #pragma unroll
        for (int j = 0; j < 8; ++j) rv += o2[i*8+j]*bs2f(wv[j]);
    }
    red[t] = rv; __syncthreads();
    for (int s = 128; s > 0; s >>= 1) { if (t < s) red[t] += red[t+s]; __syncthreads(); }
    if (t == 0) stat[0] = red[0] * (1.f/256.f);
    __syncthreads();
    float mu = stat[0];
    float dv = rv - mu;
    red[t] = dv*dv; __syncthreads();
    for (int s = 128; s > 0; s >>= 1) { if (t < s) red[t] += red[t+s]; __syncthreads(); }
    if (t == 0) stat[1] = red[0] * (1.f/256.f);
    __syncthreads();
    float rstd = rsqrtf(stat[1] + 1e-5f);
    float val = dv*rstd*ldT<F32>(lng,t) + ldT<F32>(lnb,t);
    if constexpr (F32) ((float*)outp)[q*256 + t] = val;
    else               ((bf16*)outp)[q*256 + t] = __float2bfloat16(val);
}

__global__ void __launch_bounds__(256) k4_out(
    const float* __restrict__ ws, const void* __restrict__ x,
    const void* __restrict__ outw, const void* __restrict__ lng,
    const void* __restrict__ lnb, void* __restrict__ outp)
{
    __shared__ float pl4[4][256];
    __shared__ float red[256];
    __shared__ float o2[128];
    __shared__ float stat[2];
    const bool f32 = detect_f32(x);
    if (f32) k4_body<true >(ws, x, outw, lng, lnb, outp, pl4, red, o2, stat);
    else     k4_body<false>(ws, x, outw, lng, lnb, outp, pl4, red, o2, stat);
}

// ----------------------------------------------------------------
extern "C" void kernel_launch(void* const* d_in, const int* in_sizes, int n_in,
                              void* d_out, int out_size, void* d_ws, size_t ws_size,
                              hipStream_t stream)
{
    const void* x    = d_in[0];
    const void* y    = d_in[1];
    const void* xpos = d_in[2];
    const void* ypos = d_in[3];
    const void* thw  = d_in[4];
    const void* phiw = d_in[5];
    const void* gw   = d_in[6];
    const void* qw1  = d_in[7];
    const void* qb1  = d_in[8];
    const void* qw2  = d_in[9];
    const void* qb2  = d_in[10];
    const void* kw1  = d_in[11];
    const void* kb1  = d_in[12];
    const void* kw2  = d_in[13];
    const void* kb2  = d_in[14];
    const void* outw = d_in[15];
    const void* lng  = d_in[16];
    const void* lnb  = d_in[17];
    float* ws = (float*)d_ws;

    ka_all<<<400, 256, 0, stream>>>(x, y, xpos, ypos, thw, phiw, gw,
                                    qw1, qb1, qw2, qb2, kw1, kb1, kw2, kb2, ws);
    k3_attn<<<dim3(64, 4, 2), 512, 0, stream>>>(ws);
    k4_out<<<256, 256, 0, stream>>>(ws, x, outw, lng, lnb, d_out);
}